// Round 2
// baseline (85.718 us; speedup 1.0000x reference)
//
#include <hip/hip_runtime.h>
#include <cstdint>

// Rule 30, 2 states, r=1 neighborhood, wrap. idx = L + 2C + 4R, out = (30>>idx)&1
// Truth table reduces to: new = R ^ (C | L).
//
// B=16 rows, W=2048 cells (=32 u64 words), T=1024 steps, history = T+1 states.
// Output dtype: reference returns uint8 -> harness buffer is int32 [B][T+1][W],
// values 0 / 1 (written as integers, NOT floats — round-1 lesson).

#define B 16
#define W 2048
#define T_ITERS 1024
#define WORDS 32            // W / 64
#define HIST (T_ITERS + 1)

typedef unsigned long long u64;

// ---------------- phase 1: bit-packed evolution ----------------
// One block (one wave) per batch row. Lanes 0..31 each own one 64-bit word.
// Packed history layout: pk[b][t][word] (u64) — bit i of word w = cell w*64+i
// of state t, so byte q of pk covers cells 8q..8q+7 of the flat [b][t][w]
// output; expansion is a flat byte -> 8 ints map.
__global__ __launch_bounds__(64) void ca_evolve(const float* __restrict__ x,
                                                u64* __restrict__ pk) {
    const int b = blockIdx.x;
    const int l = threadIdx.x;          // 0..63; only lanes <32 hold real words
    u64 w = 0;

    if (l < WORDS) {
        // pack 64 thresholded floats into one u64 (bit i = cell l*64+i)
        const float4* xv = (const float4*)(x + (size_t)b * W + (size_t)l * 64);
        u64 bits = 0;
        #pragma unroll
        for (int i = 0; i < 16; ++i) {
            float4 v = xv[i];
            u64 n = (v.x >= 0.5f ? 1u : 0u) | (v.y >= 0.5f ? 2u : 0u) |
                    (v.z >= 0.5f ? 4u : 0u) | (v.w >= 0.5f ? 8u : 0u);
            bits |= n << (4 * i);
        }
        w = bits;
        pk[(size_t)b * HIST * WORDS + l] = w;   // t = 0
    }

    #pragma unroll 4
    for (int t = 1; t <= T_ITERS; ++t) {
        // neighbor words (wrap across the 32-word row)
        u64 left  = __shfl(w, (l + WORDS - 1) & (WORDS - 1));
        u64 right = __shfl(w, (l + 1) & (WORDS - 1));
        u64 Lv = (w << 1) | (left >> 63);    // value of cell k-1 aligned at bit k
        u64 Rv = (w >> 1) | (right << 63);   // value of cell k+1 aligned at bit k
        w = Rv ^ (w | Lv);                   // rule 30
        if (l < WORDS)
            pk[(size_t)b * HIST * WORDS + (size_t)t * WORDS + l] = w;
    }
}

// ---------------- phase 2: bits -> int32 expansion ----------------
// One int4 (4 cells) per thread: lane i writes 16B at out+16*i -> a wave
// covers 1 KiB contiguous, perfectly coalesced. Reads are 1 byte per 2
// threads (same byte broadcast), negligible traffic (4.2 MB total).
__global__ __launch_bounds__(256) void ca_expand(const unsigned char* __restrict__ pk,
                                                 int4* __restrict__ out, int n4) {
    int i = blockIdx.x * 256 + threadIdx.x;
    if (i >= n4) return;
    unsigned int byte = pk[i >> 1];
    unsigned int nib = (byte >> ((i & 1) * 4)) & 0xFu;
    int4 f;
    f.x = (int)(nib & 1u);
    f.y = (int)((nib >> 1) & 1u);
    f.z = (int)((nib >> 2) & 1u);
    f.w = (int)((nib >> 3) & 1u);
    out[i] = f;
}

// ---------------- fallback: fused direct-int path (if ws too small) ---------
__global__ __launch_bounds__(64) void ca_fused(const float* __restrict__ x,
                                               int* __restrict__ out) {
    const int b = blockIdx.x;
    const int l = threadIdx.x;
    u64 w = 0;

    if (l < WORDS) {
        const float4* xv = (const float4*)(x + (size_t)b * W + (size_t)l * 64);
        u64 bits = 0;
        #pragma unroll
        for (int i = 0; i < 16; ++i) {
            float4 v = xv[i];
            u64 n = (v.x >= 0.5f ? 1u : 0u) | (v.y >= 0.5f ? 2u : 0u) |
                    (v.z >= 0.5f ? 4u : 0u) | (v.w >= 0.5f ? 8u : 0u);
            bits |= n << (4 * i);
        }
        w = bits;
        int4* o = (int4*)(out + (size_t)b * HIST * W + (size_t)l * 64);
        #pragma unroll
        for (int i = 0; i < 16; ++i) {
            unsigned int nib = (unsigned int)(w >> (4 * i)) & 0xFu;
            int4 f;
            f.x = (int)(nib & 1u);
            f.y = (int)((nib >> 1) & 1u);
            f.z = (int)((nib >> 2) & 1u);
            f.w = (int)((nib >> 3) & 1u);
            o[i] = f;
        }
    }

    for (int t = 1; t <= T_ITERS; ++t) {
        u64 left  = __shfl(w, (l + WORDS - 1) & (WORDS - 1));
        u64 right = __shfl(w, (l + 1) & (WORDS - 1));
        u64 Lv = (w << 1) | (left >> 63);
        u64 Rv = (w >> 1) | (right << 63);
        w = Rv ^ (w | Lv);
        if (l < WORDS) {
            int4* o = (int4*)(out + (size_t)b * HIST * W + (size_t)t * W + (size_t)l * 64);
            #pragma unroll
            for (int i = 0; i < 16; ++i) {
                unsigned int nib = (unsigned int)(w >> (4 * i)) & 0xFu;
                int4 f;
                f.x = (int)(nib & 1u);
                f.y = (int)((nib >> 1) & 1u);
                f.z = (int)((nib >> 2) & 1u);
                f.w = (int)((nib >> 3) & 1u);
                o[i] = f;
            }
        }
    }
}

extern "C" void kernel_launch(void* const* d_in, const int* in_sizes, int n_in,
                              void* d_out, int out_size, void* d_ws, size_t ws_size,
                              hipStream_t stream) {
    const float* x = (const float*)d_in[0];
    int* out = (int*)d_out;

    const size_t need = (size_t)B * HIST * WORDS * sizeof(u64);   // 4.2 MB
    if (ws_size >= need) {
        u64* pk = (u64*)d_ws;
        ca_evolve<<<B, 64, 0, stream>>>(x, pk);
        const int n4 = B * HIST * W / 4;                          // 8,396,800 int4s
        ca_expand<<<(n4 + 255) / 256, 256, 0, stream>>>((const unsigned char*)pk,
                                                        (int4*)out, n4);
    } else {
        ca_fused<<<B, 64, 0, stream>>>(x, out);
    }
}

// Round 3
// 49.838 us; speedup vs baseline: 1.7199x; 1.7199x over previous
//
#include <hip/hip_runtime.h>
#include <cstdint>

// Rule 30, 2 states, r=1, wrap. idx = L + 2C + 4R, table = bits of 30
// reduces to: new = R ^ (C | L).
//
// B=16 rows, W=2048 cells, T=1024 steps, history = T+1 states.
// Output dtype: reference returns uint8 -> harness buffer is int32 [B][T+1][W].
//
// Evolution (round 2 redesign): 64 lanes/row, each owns a u32 word (32 cells).
// Ghost-zone trick: per 16 steps, one 32-bit shuffle pair builds a 64-bit
// window [16b left halo | 32b own | 16b right halo]; the rule on the whole
// window is  win = (win>>1) ^ (win | (win<<1))  (6 VALU ops), valid region
// shrinks 1 bit/side/step, middle 32 bits valid for exactly 16 steps.
// Amortizes the ds_bpermute+lgkmcnt latency 16x vs round-1's per-step shfl.

#define B 16
#define W 2048
#define T_ITERS 1024
#define HIST (T_ITERS + 1)
#define LANES 64            // u32 words per row
#define K_STEPS 16          // steps per halo exchange (= halo width in bits)

typedef unsigned long long u64;

// ---------------- phase 1: bit-packed evolution ----------------
// One block = one wave per batch row. Lane l owns cells [32l, 32l+32).
// Packed history: pk[b][t][lane] (u32), little-endian bit i of word j =
// cell 32j+i  ->  flat byte q of pk covers cells 8q..8q+7 of [b][t][w].
__global__ __launch_bounds__(64) void ca_evolve(const float* __restrict__ x,
                                                unsigned* __restrict__ pk) {
    const int b = blockIdx.x;
    const int l = threadIdx.x;      // 0..63

    // pack 32 thresholded floats into one u32 (bit i = cell l*32+i)
    const float4* xv = (const float4*)(x + (size_t)b * W + (size_t)l * 32);
    unsigned m = 0;
    #pragma unroll
    for (int i = 0; i < 8; ++i) {
        float4 v = xv[i];
        unsigned n = (v.x >= 0.5f ? 1u : 0u) | (v.y >= 0.5f ? 2u : 0u) |
                     (v.z >= 0.5f ? 4u : 0u) | (v.w >= 0.5f ? 8u : 0u);
        m |= n << (4 * i);
    }

    unsigned* p = pk + (size_t)b * HIST * LANES + l;
    *p = m;                          // t = 0
    p += LANES;

    for (int r = 0; r < T_ITERS / K_STEPS; ++r) {
        unsigned left  = __shfl(m, (l + LANES - 1) & (LANES - 1));
        unsigned right = __shfl(m, (l + 1) & (LANES - 1));
        // window bit p = cell (32l - 16 + p); bits [16..47] = own cells
        u64 win = ((u64)(left >> 16)) | ((u64)m << 16) | ((u64)right << 48);
        #pragma unroll
        for (int j = 0; j < K_STEPS; ++j) {
            win = (win >> 1) ^ (win | (win << 1));   // rule 30 on all 64 bits
            m = (unsigned)(win >> 16);               // middle 32, valid j<=16
            *p = m;                                  // state t = r*16 + j + 1
            p += LANES;                              // folds to offset:j*256
        }
    }
}

// ---------------- phase 2: bits -> int32 expansion ----------------
// One int4 (4 cells) per thread: wave covers 1 KiB contiguous stores.
// Reads 1 byte per 2 threads (broadcast), 4.2 MB total (L2-resident).
__global__ __launch_bounds__(256) void ca_expand(const unsigned char* __restrict__ pk,
                                                 int4* __restrict__ out, int n4) {
    int i = blockIdx.x * 256 + threadIdx.x;
    if (i >= n4) return;
    unsigned int byte = pk[i >> 1];
    unsigned int nib = (byte >> ((i & 1) * 4)) & 0xFu;
    int4 f;
    f.x = (int)(nib & 1u);
    f.y = (int)((nib >> 1) & 1u);
    f.z = (int)((nib >> 2) & 1u);
    f.w = (int)((nib >> 3) & 1u);
    out[i] = f;
}

// ---------------- fallback: fused direct-int path (if ws too small) ---------
__global__ __launch_bounds__(64) void ca_fused(const float* __restrict__ x,
                                               int* __restrict__ out) {
    const int b = blockIdx.x;
    const int l = threadIdx.x;

    const float4* xv = (const float4*)(x + (size_t)b * W + (size_t)l * 32);
    unsigned m = 0;
    #pragma unroll
    for (int i = 0; i < 8; ++i) {
        float4 v = xv[i];
        unsigned n = (v.x >= 0.5f ? 1u : 0u) | (v.y >= 0.5f ? 2u : 0u) |
                     (v.z >= 0.5f ? 4u : 0u) | (v.w >= 0.5f ? 8u : 0u);
        m |= n << (4 * i);
    }

    int* o = out + (size_t)b * HIST * W + (size_t)l * 32;
    #pragma unroll
    for (int c = 0; c < 32; ++c) o[c] = (int)((m >> c) & 1u);
    o += W;

    for (int r = 0; r < T_ITERS / K_STEPS; ++r) {
        unsigned left  = __shfl(m, (l + LANES - 1) & (LANES - 1));
        unsigned right = __shfl(m, (l + 1) & (LANES - 1));
        u64 win = ((u64)(left >> 16)) | ((u64)m << 16) | ((u64)right << 48);
        #pragma unroll
        for (int j = 0; j < K_STEPS; ++j) {
            win = (win >> 1) ^ (win | (win << 1));
            m = (unsigned)(win >> 16);
            #pragma unroll
            for (int c = 0; c < 32; ++c) o[c] = (int)((m >> c) & 1u);
            o += W;
        }
    }
}

extern "C" void kernel_launch(void* const* d_in, const int* in_sizes, int n_in,
                              void* d_out, int out_size, void* d_ws, size_t ws_size,
                              hipStream_t stream) {
    const float* x = (const float*)d_in[0];
    int* out = (int*)d_out;

    const size_t need = (size_t)B * HIST * LANES * sizeof(unsigned);   // 4.2 MB
    if (ws_size >= need) {
        unsigned* pk = (unsigned*)d_ws;
        ca_evolve<<<B, 64, 0, stream>>>(x, pk);
        const int n4 = B * HIST * W / 4;                   // 8,396,800 int4s
        ca_expand<<<(n4 + 255) / 256, 256, 0, stream>>>((const unsigned char*)pk,
                                                        (int4*)out, n4);
    } else {
        ca_fused<<<B, 64, 0, stream>>>(x, out);
    }
}